// Round 11
// baseline (139.281 us; speedup 1.0000x reference)
//
#include <hip/hip_runtime.h>
#include <hip/hip_bf16.h>

typedef __attribute__((ext_vector_type(8))) short short8;
typedef __attribute__((ext_vector_type(4))) float f32x4;
typedef __attribute__((ext_vector_type(16))) float f32x16;
typedef unsigned short us;

#define B_ 2
#define S_ 2048
#define D_ 1024
#define H_ 16
#define DK_ 64
#define QSCALE 0.1803368867f  // log2(e) / 8

__device__ __forceinline__ us f2bf(float f) {
  union { float f; unsigned u; } x; x.f = f;
  unsigned r = x.u + 0x7FFFu + ((x.u >> 16) & 1u);
  return (us)(r >> 16);
}
__device__ __forceinline__ float bf2f(us h) {
  union { unsigned u; float f; } x; x.u = ((unsigned)h) << 16;
  return x.f;
}
__device__ __forceinline__ us f2bf_hw(float f) {
  __hip_bfloat16 h = __float2bfloat16(f);
  return *reinterpret_cast<us*>(&h);
}
__device__ __forceinline__ unsigned cvtpk(float lo, float hi) {
  unsigned r;
  asm("v_cvt_pk_bf16_f32 %0, %1, %2" : "=v"(r) : "v"(lo), "v"(hi));
  return r;
}

__device__ __forceinline__ void gload16(const void* g, void* l) {
  __builtin_amdgcn_global_load_lds((const __attribute__((address_space(1))) void*)g,
                                   (__attribute__((address_space(3))) void*)l, 16, 0, 0);
}

// All 7 fp32->bf16 conversions + reach row-sums in one launch (block 16384 = rs).
__global__ __launch_bounds__(256) void cvt_all(const float* __restrict__ q,
                                               const float* __restrict__ k,
                                               const float* __restrict__ v,
                                               const float* __restrict__ Wq,
                                               const float* __restrict__ Wk,
                                               const float* __restrict__ Wv,
                                               const float* __restrict__ Wo,
                                               const float* __restrict__ reaches,
                                               us* __restrict__ oq, us* __restrict__ ok,
                                               us* __restrict__ ov, us* __restrict__ oWq,
                                               us* __restrict__ oWk, us* __restrict__ oWv,
                                               us* __restrict__ oWo, float* __restrict__ rs) {
  int bid = blockIdx.x;
  if (bid >= 16384) {
    __shared__ float tmp[4];
    int t = threadIdx.x;
    for (int b = 0; b < B_; ++b) {
      float s = 0.f;
      for (int i = t; i < S_; i += 256) s += reaches[b * S_ + i];
      for (int o = 32; o > 0; o >>= 1) s += __shfl_down(s, o, 64);
      if ((t & 63) == 0) tmp[t >> 6] = s;
      __syncthreads();
      if (t == 0) rs[b] = tmp[0] + tmp[1] + tmp[2] + tmp[3];
      __syncthreads();
    }
    return;
  }
  const float* in; us* out; int off;
  if (bid < 12288) {
    int t = bid >> 12;
    in = (t == 0) ? q : (t == 1) ? k : v;
    out = (t == 0) ? oq : (t == 1) ? ok : ov;
    off = (bid & 4095) * 1024;
  } else {
    int t = (bid - 12288) >> 10;
    in = (t == 0) ? Wq : (t == 1) ? Wk : (t == 2) ? Wv : Wo;
    out = (t == 0) ? oWq : (t == 1) ? oWk : (t == 2) ? oWv : oWo;
    off = ((bid - 12288) & 1023) * 1024;
  }
  int i = off + threadIdx.x * 4;
  float4 val = *reinterpret_cast<const float4*>(in + i);
  ushort4 o;
  o.x = f2bf(val.x); o.y = f2bf(val.y); o.z = f2bf(val.z); o.w = f2bf(val.w);
  *reinterpret_cast<ushort4*>(out + i) = o;
}

// GEMM 128x128 tile, BK=32, triple-buffered LDS + global_load_lds w16 + counted vmcnt.
__device__ __forceinline__ void gemm_core_hs(const us* __restrict__ A, const us* __restrict__ Bt,
                                             us* __restrict__ outH, float oscale) {
  __shared__ __align__(16) us lA[3][128 * 32];
  __shared__ __align__(16) us lB[3][128 * 32];
  const int tid = threadIdx.x;
  const int bm = blockIdx.x >> 3, bn = blockIdx.x & 7;
  const int w = tid >> 6, lane = tid & 63;
  const int wr = (w >> 1) * 64, wc = (w & 1) * 64;
  const int lr = lane & 15, lg = lane >> 4;

  f32x4 acc[4][4];
#pragma unroll
  for (int i = 0; i < 4; ++i)
#pragma unroll
    for (int j = 0; j < 4; ++j) acc[i][j] = (f32x4){0.f, 0.f, 0.f, 0.f};

  const int crow = lane >> 2, ce8 = (lane & 3) * 8;
  const us* A0 = A + (size_t)(bm * 128 + w * 32 + crow) * 1024 + ce8;
  const us* A1 = A0 + (size_t)16 * 1024;
  const us* B0 = Bt + (size_t)(bn * 128 + w * 32 + crow) * 1024 + ce8;
  const us* B1 = B0 + (size_t)16 * 1024;
  const int dA0 = (w * 32) * 32, dA1 = (w * 32 + 16) * 32;

  gload16(A0, &lA[0][dA0]);
  gload16(A1, &lA[0][dA1]);
  gload16(B0, &lB[0][dA0]);
  gload16(B1, &lB[0][dA1]);

  int cur = 0, nxt = 1;
  for (int kt = 0; kt < 32; ++kt) {
    if (kt < 31) {
      int ko = (kt + 1) * 32;
      gload16(A0 + ko, &lA[nxt][dA0]);
      gload16(A1 + ko, &lA[nxt][dA1]);
      gload16(B0 + ko, &lB[nxt][dA0]);
      gload16(B1 + ko, &lB[nxt][dA1]);
      asm volatile("s_waitcnt vmcnt(4)" ::: "memory");
    } else {
      asm volatile("s_waitcnt vmcnt(0)" ::: "memory");
    }
    __builtin_amdgcn_s_barrier();
    __builtin_amdgcn_sched_barrier(0);

    short8 af[4], bfr[4];
#pragma unroll
    for (int i = 0; i < 4; ++i)
      af[i] = *reinterpret_cast<const short8*>(&lA[cur][(wr + i * 16 + lr) * 32 + lg * 8]);
#pragma unroll
    for (int j = 0; j < 4; ++j)
      bfr[j] = *reinterpret_cast<const short8*>(&lB[cur][(wc + j * 16 + lr) * 32 + lg * 8]);
    __builtin_amdgcn_s_setprio(1);
#pragma unroll
    for (int i = 0; i < 4; ++i)
#pragma unroll
      for (int j = 0; j < 4; ++j)
        acc[i][j] = __builtin_amdgcn_mfma_f32_16x16x32_bf16(af[i], bfr[j], acc[i][j], 0, 0, 0);
    __builtin_amdgcn_s_setprio(0);

    cur = nxt;
    nxt = (nxt == 2) ? 0 : nxt + 1;
  }
#pragma unroll
  for (int i = 0; i < 4; ++i)
#pragma unroll
    for (int j = 0; j < 4; ++j)
#pragma unroll
      for (int ii = 0; ii < 4; ++ii) {
        int r = bm * 128 + wr + i * 16 + lg * 4 + ii;
        int c = bn * 128 + wc + j * 16 + lr;
        float v = acc[i][j][ii] * oscale;
        int b = r >> 11, s = r & (S_ - 1), h = c >> 6, dk = c & 63;
        outH[(((size_t)(b * H_ + h) * S_ + s) * DK_) + dk] = f2bf(v);
      }
}

__global__ __launch_bounds__(256) void proj_gemm(const us* __restrict__ q_bf,
                                                 const us* __restrict__ k_bf,
                                                 const us* __restrict__ v_bf,
                                                 const us* __restrict__ Wq_bf,
                                                 const us* __restrict__ Wk_bf,
                                                 const us* __restrict__ Wv_bf,
                                                 us* __restrict__ Qh, us* __restrict__ Kh,
                                                 us* __restrict__ Vh) {
  if (blockIdx.y == 0) gemm_core_hs(q_bf, Wq_bf, Qh, QSCALE);
  else if (blockIdx.y == 1) gemm_core_hs(k_bf, Wk_bf, Kh, 1.0f);
  else gemm_core_hs(v_bf, Wv_bf, Vh, 1.0f);
}

// Wo GEMM: 128x64 tile, triple-buffered + counted vmcnt, fp32 output.
__global__ __launch_bounds__(256) void wo_gemm(const us* __restrict__ A,
                                               const us* __restrict__ Bt,
                                               float* __restrict__ outF) {
  __shared__ __align__(16) us lA[3][128 * 32];
  __shared__ __align__(16) us lB[3][64 * 32];
  const int tid = threadIdx.x;
  const int bm = blockIdx.x >> 4, bn = blockIdx.x & 15;
  const int w = tid >> 6, lane = tid & 63;
  const int lr = lane & 15, lg = lane >> 4;

  f32x4 acc[2][4];
#pragma unroll
  for (int i = 0; i < 2; ++i)
#pragma unroll
    for (int j = 0; j < 4; ++j) acc[i][j] = (f32x4){0.f, 0.f, 0.f, 0.f};

  const int crow = lane >> 2, ce8 = (lane & 3) * 8;
  const us* A0 = A + (size_t)(bm * 128 + w * 32 + crow) * 1024 + ce8;
  const us* A1 = A0 + (size_t)16 * 1024;
  const us* B0 = Bt + (size_t)(bn * 64 + w * 16 + crow) * 1024 + ce8;
  const int dA0 = (w * 32) * 32, dA1 = (w * 32 + 16) * 32, dB0 = (w * 16) * 32;

  gload16(A0, &lA[0][dA0]);
  gload16(A1, &lA[0][dA1]);
  gload16(B0, &lB[0][dB0]);

  int cur = 0, nxt = 1;
  for (int kt = 0; kt < 32; ++kt) {
    if (kt < 31) {
      int ko = (kt + 1) * 32;
      gload16(A0 + ko, &lA[nxt][dA0]);
      gload16(A1 + ko, &lA[nxt][dA1]);
      gload16(B0 + ko, &lB[nxt][dB0]);
      asm volatile("s_waitcnt vmcnt(3)" ::: "memory");
    } else {
      asm volatile("s_waitcnt vmcnt(0)" ::: "memory");
    }
    __builtin_amdgcn_s_barrier();
    __builtin_amdgcn_sched_barrier(0);

    short8 af[2], bfr[4];
#pragma unroll
    for (int i = 0; i < 2; ++i)
      af[i] = *reinterpret_cast<const short8*>(&lA[cur][(w * 32 + i * 16 + lr) * 32 + lg * 8]);
#pragma unroll
    for (int j = 0; j < 4; ++j)
      bfr[j] = *reinterpret_cast<const short8*>(&lB[cur][(j * 16 + lr) * 32 + lg * 8]);
    __builtin_amdgcn_s_setprio(1);
#pragma unroll
    for (int i = 0; i < 2; ++i)
#pragma unroll
      for (int j = 0; j < 4; ++j)
        acc[i][j] = __builtin_amdgcn_mfma_f32_16x16x32_bf16(af[i], bfr[j], acc[i][j], 0, 0, 0);
    __builtin_amdgcn_s_setprio(0);

    cur = nxt;
    nxt = (nxt == 2) ? 0 : nxt + 1;
  }
#pragma unroll
  for (int i = 0; i < 2; ++i)
#pragma unroll
    for (int j = 0; j < 4; ++j)
#pragma unroll
      for (int ii = 0; ii < 4; ++ii) {
        int r = bm * 128 + w * 32 + i * 16 + lg * 4 + ii;
        int c = bn * 64 + j * 16 + lr;
        outF[(size_t)r * 1024 + c] = acc[i][j][ii];
      }
}

// Vh [B,H,S,DK] -> VhTw [B,H,DK,S] with reach weighting folded in.
__global__ __launch_bounds__(256) void transp_kernel(const us* __restrict__ Vh,
                                                     const float* __restrict__ reaches,
                                                     us* __restrict__ VhTw) {
  __shared__ us t[64 * 68];
  const int bh = blockIdx.x >> 5, st = blockIdx.x & 31;
  const int b = bh >> 4;
  const size_t base = (size_t)bh * S_ * DK_;
  const int r = threadIdx.x >> 3, e8 = (threadIdx.x & 7) * 8;
#pragma unroll
  for (int h2 = 0; h2 < 2; ++h2) {
    int row = r + h2 * 32;
    *reinterpret_cast<short8*>(&t[row * 68 + e8]) =
        *reinterpret_cast<const short8*>(&Vh[base + (size_t)(st * 64 + row) * DK_ + e8]);
  }
  __syncthreads();
#pragma unroll
  for (int h2 = 0; h2 < 2; ++h2) {
    int dk = (threadIdx.x >> 3) + h2 * 32;
    int sc = (threadIdx.x & 7) * 8;
    short8 v;
#pragma unroll
    for (int j = 0; j < 8; ++j) {
      float rw = reaches[b * S_ + st * 64 + sc + j];
      v[j] = (short)f2bf_hw(bf2f(t[(sc + j) * 68 + dk]) * rw);
    }
    *reinterpret_cast<short8*>(&VhTw[base + (size_t)dk * S_ + st * 64 + sc]) = v;
  }
}

// 32x32-MFMA streaming-softmax attention, swapped QK^T + in-register P.
// 64-row q-tile per block (grid 1024 = 4 blocks/CU = 4 waves/SIMD).
// Waves 2x2: wq = q-half (32 rows), wk = k-half (32 of 64 k-cols).
// K/V' double-buffered swizzled LDS, one barrier/kt; end-of-kernel O/l merge.
__global__ __launch_bounds__(256, 4) void attn_kernel(const us* __restrict__ Qh,
                                                      const us* __restrict__ Kh,
                                                      const us* __restrict__ Vh,
                                                      const us* __restrict__ VhTw,
                                                      const float* __restrict__ reaches,
                                                      const float* __restrict__ rsum,
                                                      us* __restrict__ concat) {
  __shared__ __align__(16) us sbuf[4][4096];  // [0],[1]=K bufs; [2],[3]=V bufs
  __shared__ float diagP[64];
  __shared__ float lown[64];
  __shared__ float lpart[64];
  float* mscr = reinterpret_cast<float*>(&sbuf[0][0]);  // merge scratch 64x64 f32 (16 KB)

  const int tid = threadIdx.x;
  const int bid = ((blockIdx.x & 7) << 7) | (blockIdx.x >> 3);  // XCD swizzle (1024 = 8*128)
  const int qt = bid & 31;
  const int bh = bid >> 5;
  const int b = bh >> 4, h = bh & 15;
  const size_t base = (size_t)bh * S_ * DK_;

  const int w = tid >> 6, lane = tid & 63;
  const int wq = w >> 1, wk = w & 1;
  const int l31 = lane & 31, hh = lane >> 5, l7 = lane & 7;
  const int h4 = hh * 4;
  const int r2 = tid >> 3, e8 = (tid & 7) * 8;

  // Q fragments (B-operand for swapped QK): q rows = qt*64 + wq*32 + l31
  short8 aq[4];
  {
    const us* qp = &Qh[base + (size_t)(qt * 64 + wq * 32 + l31) * DK_ + hh * 8];
#pragma unroll
    for (int dk = 0; dk < 4; ++dk)
      aq[dk] = *reinterpret_cast<const short8*>(qp + dk * 16);
  }

  // loop-invariant swizzled LDS read offsets
  int rdK[4], rdV[2][2];
#pragma unroll
  for (int dk = 0; dk < 4; ++dk)
    rdK[dk] = (wk * 32 + l31) * 64 + (((dk * 2 + hh) ^ l7) << 3);
#pragma unroll
  for (int dc = 0; dc < 2; ++dc)
#pragma unroll
    for (int ks = 0; ks < 2; ++ks)
      rdV[dc][ks] = (dc * 32 + l31) * 64 + (((wk * 4 + ks * 2 + hh) ^ l7) << 3);

  const int wslot = ((tid & 7) ^ (r2 & 7)) << 3;
  const int wK0 = r2 * 64 + wslot, wK1 = (r2 + 32) * 64 + wslot;

  // prologue: stage tile 0 into buffer 0
  short8 pk0, pk1, pv0, pv1;
  pk0 = *reinterpret_cast<const short8*>(&Kh[base + (size_t)r2 * DK_ + e8]);
  pk1 = *reinterpret_cast<const short8*>(&Kh[base + (size_t)(r2 + 32) * DK_ + e8]);
  pv0 = *reinterpret_cast<const short8*>(&VhTw[base + (size_t)r2 * S_ + e8]);
  pv1 = *reinterpret_cast<const short8*>(&VhTw[base + (size_t)(r2 + 32) * S_ + e8]);
  *reinterpret_cast<short8*>(&sbuf[0][wK0]) = pk0;
  *reinterpret_cast<short8*>(&sbuf[0][wK1]) = pk1;
  *reinterpret_cast<short8*>(&sbuf[2][wK0]) = pv0;
  *reinterpret_cast<short8*>(&sbuf[2][wK1]) = pv1;
  __syncthreads();

  f32x16 oacc0, oacc1;
  float lacc = 0.f;
#pragma unroll
  for (int r = 0; r < 16; ++r) { oacc0[r] = 0.f; oacc1[r] = 0.f; }

  for (int kt = 0; kt < 32; ++kt) {
    const int cur = kt & 1;
    if (kt < 31) {
      int nt = kt + 1;
      pk0 = *reinterpret_cast<const short8*>(&Kh[base + (size_t)(nt * 64 + r2) * DK_ + e8]);
      pk1 = *reinterpret_cast<const short8*>(&Kh[base + (size_t)(nt * 64 + r2 + 32) * DK_ + e8]);
      pv0 = *reinterpret_cast<const short8*>(&VhTw[base + (size_t)r2 * S_ + nt * 64 + e8]);
      pv1 = *reinterpret_cast<const short8*>(&VhTw[base + (size_t)(r2 + 32) * S_ + nt * 64 + e8]);
    }

    // swapped QK^T over this wave's k-half: st[k=crow+32wk][q=l31+32wq]
    f32x16 st;
#pragma unroll
    for (int r = 0; r < 16; ++r) st[r] = 0.f;
    __builtin_amdgcn_s_setprio(1);
#pragma unroll
    for (int dk = 0; dk < 4; ++dk) {
      short8 k0 = *reinterpret_cast<const short8*>(&sbuf[cur][rdK[dk]]);
      st = __builtin_amdgcn_mfma_f32_32x32x16_bf16(k0, aq[dk], st, 0, 0, 0);
    }
    __builtin_amdgcn_s_setprio(0);

    // streaming softmax fully in-register
    float e[16];
#pragma unroll
    for (int r = 0; r < 16; ++r) {
      e[r] = __builtin_amdgcn_exp2f(st[r]);
      lacc += e[r];
    }
    if (kt == qt && wq == wk) {  // diagonal lives in this tile/k-half
#pragma unroll
      for (int r = 0; r < 16; ++r) {
        int kk = (r & 3) + 8 * (r >> 2) + h4;
        if (kk == l31) diagP[wq * 32 + l31] = e[r];
      }
    }

    // P -> bf16 A-frags via cvt_pk + permlane32_swap
    short8 pa[2];
#pragma unroll
    for (int ks = 0; ks < 2; ++ks) {
      const int ro = ks * 8;
      unsigned d0 = cvtpk(e[ro + 0], e[ro + 1]);
      unsigned s0 = cvtpk(e[ro + 4], e[ro + 5]);
      unsigned d1 = cvtpk(e[ro + 2], e[ro + 3]);
      unsigned s1 = cvtpk(e[ro + 6], e[ro + 7]);
      asm("v_permlane32_swap_b32 %0, %1" : "+v"(d0), "+v"(s0));
      asm("v_permlane32_swap_b32 %0, %1" : "+v"(d1), "+v"(s1));
      union { unsigned u[4]; short8 v; } pk;
      pk.u[0] = d0; pk.u[1] = d1; pk.u[2] = s0; pk.u[3] = s1;
      pa[ks] = pk.v;
    }

    // PV over this wave's k-half: O[q32][d64] += P V'
    __builtin_amdgcn_s_setprio(1);
#pragma unroll
    for (int ks = 0; ks < 2; ++ks) {
      short8 bv0 = *reinterpret_cast<const short8*>(&sbuf[2 + cur][rdV[0][ks]]);
      oacc0 = __builtin_amdgcn_mfma_f32_32x32x16_bf16(pa[ks], bv0, oacc0, 0, 0, 0);
      short8 bv1 = *reinterpret_cast<const short8*>(&sbuf[2 + cur][rdV[1][ks]]);
      oacc1 = __builtin_amdgcn_mfma_f32_32x32x16_bf16(pa[ks], bv1, oacc1, 0, 0, 0);
    }
    __builtin_amdgcn_s_setprio(0);

    if (kt < 31) {
      const int nx = cur ^ 1;
      *reinterpret_cast<short8*>(&sbuf[nx][wK0]) = pk0;
      *reinterpret_cast<short8*>(&sbuf[nx][wK1]) = pk1;
      *reinterpret_cast<short8*>(&sbuf[2 + nx][wK0]) = pv0;
      *reinterpret_cast<short8*>(&sbuf[2 + nx][wK1]) = pv1;
    }
    __syncthreads();
  }

  // merge l across hh halves (per-lane partial over this wave's 32 k)
  lacc += __shfl_xor(lacc, 32, 64);
  __syncthreads();  // all buffer reads done; safe to overlay scratch on K bufs

  if (wk == 1) {
#pragma unroll
    for (int r = 0; r < 16; ++r) {
      int q = wq * 32 + (r & 3) + 8 * (r >> 2) + h4;
      mscr[q * 64 + l31] = oacc0[r];
      mscr[q * 64 + 32 + l31] = oacc1[r];
    }
    if (hh == 0) lpart[wq * 32 + l31] = lacc;
  } else {
    if (hh == 0) lown[wq * 32 + l31] = lacc;
  }
  __syncthreads();

  if (wk == 0) {
    const float rb = rsum[b];
#pragma unroll
    for (int r = 0; r < 16; ++r) {
      const int q = wq * 32 + (r & 3) + 8 * (r >> 2) + h4;
      const int qg = qt * 64 + q;
      const float rq = reaches[b * S_ + qg];
      const float contrib = (rb - rq) / (rb + 1e-9f) * (1.f - rq) * 100.f;
      const float corr = 0.999999f * diagP[q] * rq;
      const float linv = 1.0f / (lown[q] + lpart[q]);
#pragma unroll
      for (int dc = 0; dc < 2; ++dc) {
        int d = dc * 32 + l31;
        float vhv = bf2f(Vh[base + (size_t)qg * DK_ + d]);
        float oaccv = (dc ? oacc1[r] : oacc0[r]) + mscr[q * 64 + d];
        float pv = (oaccv - corr * vhv) * linv;
        float o = (vhv - pv) * contrib;
        concat[((size_t)(b * S_ + qg)) * D_ + h * 64 + d] = f2bf(o);
      }
    }
  }
}

extern "C" void kernel_launch(void* const* d_in, const int* in_sizes, int n_in,
                              void* d_out, int out_size, void* d_ws, size_t ws_size,
                              hipStream_t stream) {
  const float* q = (const float*)d_in[0];
  const float* k = (const float*)d_in[1];
  const float* v = (const float*)d_in[2];
  const float* reaches = (const float*)d_in[3];
  const float* Wq = (const float*)d_in[4];
  const float* Wk = (const float*)d_in[5];
  const float* Wv = (const float*)d_in[6];
  const float* Wo = (const float*)d_in[7];

  const size_t NQKV = (size_t)B_ * S_ * D_;
  const size_t NW = (size_t)D_ * D_;

  us* q_bf = (us*)d_ws;
  us* k_bf = q_bf + NQKV;
  us* v_bf = k_bf + NQKV;
  us* Wq_bf = v_bf + NQKV;
  us* Wk_bf = Wq_bf + NW;
  us* Wv_bf = Wk_bf + NW;
  us* Wo_bf = Wv_bf + NW;
  us* Qh = Wo_bf + NW;
  us* Kh = Qh + NQKV;
  us* Vh = Kh + NQKV;
  us* concat = Vh + NQKV;
  float* rs = (float*)(concat + NQKV);
  us* VhTw = q_bf;  // alias: q_bf dead after proj_gemm

  cvt_all<<<16385, 256, 0, stream>>>(q, k, v, Wq, Wk, Wv, Wo, reaches,
                                     q_bf, k_bf, v_bf, Wq_bf, Wk_bf, Wv_bf, Wo_bf, rs);

  proj_gemm<<<dim3(256, 3), 256, 0, stream>>>(q_bf, k_bf, v_bf, Wq_bf, Wk_bf, Wv_bf, Qh, Kh, Vh);
  transp_kernel<<<B_ * H_ * (S_ / 64), 256, 0, stream>>>(Vh, reaches, VhTw);

  attn_kernel<<<B_ * H_ * (S_ / 64), 256, 0, stream>>>(Qh, Kh, Vh, VhTw, reaches, rs, concat);

  wo_gemm<<<512, 256, 0, stream>>>(concat, Wo_bf, (float*)d_out);
}

// Round 12
// 126.810 us; speedup vs baseline: 1.0983x; 1.0983x over previous
//
#include <hip/hip_runtime.h>
#include <hip/hip_bf16.h>

typedef __attribute__((ext_vector_type(8))) short short8;
typedef __attribute__((ext_vector_type(4))) float f32x4;
typedef __attribute__((ext_vector_type(16))) float f32x16;
typedef unsigned short us;

#define B_ 2
#define S_ 2048
#define D_ 1024
#define H_ 16
#define DK_ 64
#define QSCALE 0.1803368867f  // log2(e) / 8

__device__ __forceinline__ us f2bf(float f) {
  union { float f; unsigned u; } x; x.f = f;
  unsigned r = x.u + 0x7FFFu + ((x.u >> 16) & 1u);
  return (us)(r >> 16);
}
__device__ __forceinline__ float bf2f(us h) {
  union { unsigned u; float f; } x; x.u = ((unsigned)h) << 16;
  return x.f;
}
__device__ __forceinline__ us f2bf_hw(float f) {
  __hip_bfloat16 h = __float2bfloat16(f);
  return *reinterpret_cast<us*>(&h);
}
__device__ __forceinline__ unsigned cvtpk(float lo, float hi) {
  unsigned r;
  asm("v_cvt_pk_bf16_f32 %0, %1, %2" : "=v"(r) : "v"(lo), "v"(hi));
  return r;
}

__device__ __forceinline__ void gload16(const void* g, void* l) {
  __builtin_amdgcn_global_load_lds((const __attribute__((address_space(1))) void*)g,
                                   (__attribute__((address_space(3))) void*)l, 16, 0, 0);
}

// All 7 fp32->bf16 conversions + reach row-sums in one launch (block 16384 = rs).
__global__ __launch_bounds__(256) void cvt_all(const float* __restrict__ q,
                                               const float* __restrict__ k,
                                               const float* __restrict__ v,
                                               const float* __restrict__ Wq,
                                               const float* __restrict__ Wk,
                                               const float* __restrict__ Wv,
                                               const float* __restrict__ Wo,
                                               const float* __restrict__ reaches,
                                               us* __restrict__ oq, us* __restrict__ ok,
                                               us* __restrict__ ov, us* __restrict__ oWq,
                                               us* __restrict__ oWk, us* __restrict__ oWv,
                                               us* __restrict__ oWo, float* __restrict__ rs) {
  int bid = blockIdx.x;
  if (bid >= 16384) {
    __shared__ float tmp[4];
    int t = threadIdx.x;
    for (int b = 0; b < B_; ++b) {
      float s = 0.f;
      for (int i = t; i < S_; i += 256) s += reaches[b * S_ + i];
      for (int o = 32; o > 0; o >>= 1) s += __shfl_down(s, o, 64);
      if ((t & 63) == 0) tmp[t >> 6] = s;
      __syncthreads();
      if (t == 0) rs[b] = tmp[0] + tmp[1] + tmp[2] + tmp[3];
      __syncthreads();
    }
    return;
  }
  const float* in; us* out; int off;
  if (bid < 12288) {
    int t = bid >> 12;
    in = (t == 0) ? q : (t == 1) ? k : v;
    out = (t == 0) ? oq : (t == 1) ? ok : ov;
    off = (bid & 4095) * 1024;
  } else {
    int t = (bid - 12288) >> 10;
    in = (t == 0) ? Wq : (t == 1) ? Wk : (t == 2) ? Wv : Wo;
    out = (t == 0) ? oWq : (t == 1) ? oWk : (t == 2) ? oWv : oWo;
    off = ((bid - 12288) & 1023) * 1024;
  }
  int i = off + threadIdx.x * 4;
  float4 val = *reinterpret_cast<const float4*>(in + i);
  ushort4 o;
  o.x = f2bf(val.x); o.y = f2bf(val.y); o.z = f2bf(val.z); o.w = f2bf(val.w);
  *reinterpret_cast<ushort4*>(out + i) = o;
}

// GEMM 128x128 tile, BK=32, triple-buffered LDS + global_load_lds w16 + counted vmcnt.
// Chunked XCD swizzle: each XCD gets 4 contiguous bm rows x all 8 bn (3 MB, L2-resident).
__device__ __forceinline__ void gemm_core_hs(const us* __restrict__ A, const us* __restrict__ Bt,
                                             us* __restrict__ outH, float oscale) {
  __shared__ __align__(16) us lA[3][128 * 32];
  __shared__ __align__(16) us lB[3][128 * 32];
  const int tid = threadIdx.x;
  const int swz = (blockIdx.x & 7) * 32 + (blockIdx.x >> 3);  // 256 = 8*32, bijective
  const int bm = swz >> 3, bn = swz & 7;
  const int w = tid >> 6, lane = tid & 63;
  const int wr = (w >> 1) * 64, wc = (w & 1) * 64;
  const int lr = lane & 15, lg = lane >> 4;

  f32x4 acc[4][4];
#pragma unroll
  for (int i = 0; i < 4; ++i)
#pragma unroll
    for (int j = 0; j < 4; ++j) acc[i][j] = (f32x4){0.f, 0.f, 0.f, 0.f};

  const int crow = lane >> 2, ce8 = (lane & 3) * 8;
  const us* A0 = A + (size_t)(bm * 128 + w * 32 + crow) * 1024 + ce8;
  const us* A1 = A0 + (size_t)16 * 1024;
  const us* B0 = Bt + (size_t)(bn * 128 + w * 32 + crow) * 1024 + ce8;
  const us* B1 = B0 + (size_t)16 * 1024;
  const int dA0 = (w * 32) * 32, dA1 = (w * 32 + 16) * 32;

  gload16(A0, &lA[0][dA0]);
  gload16(A1, &lA[0][dA1]);
  gload16(B0, &lB[0][dA0]);
  gload16(B1, &lB[0][dA1]);

  int cur = 0, nxt = 1;
  for (int kt = 0; kt < 32; ++kt) {
    if (kt < 31) {
      int ko = (kt + 1) * 32;
      gload16(A0 + ko, &lA[nxt][dA0]);
      gload16(A1 + ko, &lA[nxt][dA1]);
      gload16(B0 + ko, &lB[nxt][dA0]);
      gload16(B1 + ko, &lB[nxt][dA1]);
      asm volatile("s_waitcnt vmcnt(4)" ::: "memory");
    } else {
      asm volatile("s_waitcnt vmcnt(0)" ::: "memory");
    }
    __builtin_amdgcn_s_barrier();
    __builtin_amdgcn_sched_barrier(0);

    short8 af[4], bfr[4];
#pragma unroll
    for (int i = 0; i < 4; ++i)
      af[i] = *reinterpret_cast<const short8*>(&lA[cur][(wr + i * 16 + lr) * 32 + lg * 8]);
#pragma unroll
    for (int j = 0; j < 4; ++j)
      bfr[j] = *reinterpret_cast<const short8*>(&lB[cur][(wc + j * 16 + lr) * 32 + lg * 8]);
    __builtin_amdgcn_s_setprio(1);
#pragma unroll
    for (int i = 0; i < 4; ++i)
#pragma unroll
      for (int j = 0; j < 4; ++j)
        acc[i][j] = __builtin_amdgcn_mfma_f32_16x16x32_bf16(af[i], bfr[j], acc[i][j], 0, 0, 0);
    __builtin_amdgcn_s_setprio(0);

    cur = nxt;
    nxt = (nxt == 2) ? 0 : nxt + 1;
  }
#pragma unroll
  for (int i = 0; i < 4; ++i)
#pragma unroll
    for (int j = 0; j < 4; ++j)
#pragma unroll
      for (int ii = 0; ii < 4; ++ii) {
        int r = bm * 128 + wr + i * 16 + lg * 4 + ii;
        int c = bn * 128 + wc + j * 16 + lr;
        float v = acc[i][j][ii] * oscale;
        int b = r >> 11, s = r & (S_ - 1), h = c >> 6, dk = c & 63;
        outH[(((size_t)(b * H_ + h) * S_ + s) * DK_) + dk] = f2bf(v);
      }
}

__global__ __launch_bounds__(256) void proj_gemm(const us* __restrict__ q_bf,
                                                 const us* __restrict__ k_bf,
                                                 const us* __restrict__ v_bf,
                                                 const us* __restrict__ Wq_bf,
                                                 const us* __restrict__ Wk_bf,
                                                 const us* __restrict__ Wv_bf,
                                                 us* __restrict__ Qh, us* __restrict__ Kh,
                                                 us* __restrict__ Vh) {
  if (blockIdx.y == 0) gemm_core_hs(q_bf, Wq_bf, Qh, QSCALE);
  else if (blockIdx.y == 1) gemm_core_hs(k_bf, Wk_bf, Kh, 1.0f);
  else gemm_core_hs(v_bf, Wv_bf, Vh, 1.0f);
}

// Wo GEMM: 128x64 tile, triple-buffered + counted vmcnt, fp32 output, chunked swizzle.
__global__ __launch_bounds__(256) void wo_gemm(const us* __restrict__ A,
                                               const us* __restrict__ Bt,
                                               float* __restrict__ outF) {
  __shared__ __align__(16) us lA[3][128 * 32];
  __shared__ __align__(16) us lB[3][64 * 32];
  const int tid = threadIdx.x;
  const int swz = (blockIdx.x & 7) * 64 + (blockIdx.x >> 3);  // 512 = 8*64, bijective
  const int bm = swz >> 4, bn = swz & 15;
  const int w = tid >> 6, lane = tid & 63;
  const int lr = lane & 15, lg = lane >> 4;

  f32x4 acc[2][4];
#pragma unroll
  for (int i = 0; i < 2; ++i)
#pragma unroll
    for (int j = 0; j < 4; ++j) acc[i][j] = (f32x4){0.f, 0.f, 0.f, 0.f};

  const int crow = lane >> 2, ce8 = (lane & 3) * 8;
  const us* A0 = A + (size_t)(bm * 128 + w * 32 + crow) * 1024 + ce8;
  const us* A1 = A0 + (size_t)16 * 1024;
  const us* B0 = Bt + (size_t)(bn * 64 + w * 16 + crow) * 1024 + ce8;
  const int dA0 = (w * 32) * 32, dA1 = (w * 32 + 16) * 32, dB0 = (w * 16) * 32;

  gload16(A0, &lA[0][dA0]);
  gload16(A1, &lA[0][dA1]);
  gload16(B0, &lB[0][dB0]);

  int cur = 0, nxt = 1;
  for (int kt = 0; kt < 32; ++kt) {
    if (kt < 31) {
      int ko = (kt + 1) * 32;
      gload16(A0 + ko, &lA[nxt][dA0]);
      gload16(A1 + ko, &lA[nxt][dA1]);
      gload16(B0 + ko, &lB[nxt][dB0]);
      asm volatile("s_waitcnt vmcnt(3)" ::: "memory");
    } else {
      asm volatile("s_waitcnt vmcnt(0)" ::: "memory");
    }
    __builtin_amdgcn_s_barrier();
    __builtin_amdgcn_sched_barrier(0);

    short8 af[2], bfr[4];
#pragma unroll
    for (int i = 0; i < 2; ++i)
      af[i] = *reinterpret_cast<const short8*>(&lA[cur][(w * 32 + i * 16 + lr) * 32 + lg * 8]);
#pragma unroll
    for (int j = 0; j < 4; ++j)
      bfr[j] = *reinterpret_cast<const short8*>(&lB[cur][(j * 16 + lr) * 32 + lg * 8]);
    __builtin_amdgcn_s_setprio(1);
#pragma unroll
    for (int i = 0; i < 2; ++i)
#pragma unroll
      for (int j = 0; j < 4; ++j)
        acc[i][j] = __builtin_amdgcn_mfma_f32_16x16x32_bf16(af[i], bfr[j], acc[i][j], 0, 0, 0);
    __builtin_amdgcn_s_setprio(0);

    cur = nxt;
    nxt = (nxt == 2) ? 0 : nxt + 1;
  }
#pragma unroll
  for (int i = 0; i < 2; ++i)
#pragma unroll
    for (int j = 0; j < 4; ++j)
#pragma unroll
      for (int ii = 0; ii < 4; ++ii) {
        int r = bm * 128 + w * 32 + i * 16 + lg * 4 + ii;
        int c = bn * 64 + j * 16 + lr;
        outF[(size_t)r * 1024 + c] = acc[i][j][ii];
      }
}

// Vh [B,H,S,DK] -> VhTw [B,H,DK,S] with reach weighting folded in.
__global__ __launch_bounds__(256) void transp_kernel(const us* __restrict__ Vh,
                                                     const float* __restrict__ reaches,
                                                     us* __restrict__ VhTw) {
  __shared__ us t[64 * 68];
  const int bh = blockIdx.x >> 5, st = blockIdx.x & 31;
  const int b = bh >> 4;
  const size_t base = (size_t)bh * S_ * DK_;
  const int r = threadIdx.x >> 3, e8 = (threadIdx.x & 7) * 8;
#pragma unroll
  for (int h2 = 0; h2 < 2; ++h2) {
    int row = r + h2 * 32;
    *reinterpret_cast<short8*>(&t[row * 68 + e8]) =
        *reinterpret_cast<const short8*>(&Vh[base + (size_t)(st * 64 + row) * DK_ + e8]);
  }
  __syncthreads();
#pragma unroll
  for (int h2 = 0; h2 < 2; ++h2) {
    int dk = (threadIdx.x >> 3) + h2 * 32;
    int sc = (threadIdx.x & 7) * 8;
    short8 v;
#pragma unroll
    for (int j = 0; j < 8; ++j) {
      float rw = reaches[b * S_ + st * 64 + sc + j];
      v[j] = (short)f2bf_hw(bf2f(t[(sc + j) * 68 + dk]) * rw);
    }
    *reinterpret_cast<short8*>(&VhTw[base + (size_t)dk * S_ + st * 64 + sc]) = v;
  }
}

// r8 attention (best measured: 51.4 us): 32x32-MFMA, swapped QK^T + in-register P,
// 4 waves x 32 q-rows = 128-row q-tile, K/V' double-buffered swizzled LDS,
// reg-prefetch staging, one barrier pair per kt.
__global__ __launch_bounds__(256, 2) void attn_kernel(const us* __restrict__ Qh,
                                                      const us* __restrict__ Kh,
                                                      const us* __restrict__ Vh,
                                                      const us* __restrict__ VhTw,
                                                      const float* __restrict__ reaches,
                                                      const float* __restrict__ rsum,
                                                      us* __restrict__ concat) {
  __shared__ __align__(16) us lK2[2][64 * 64];
  __shared__ __align__(16) us vT2[2][64 * 64];
  __shared__ float diagP[128];
  __shared__ float lsum[128];

  const int tid = threadIdx.x;
  const int bid = ((blockIdx.x & 7) << 6) | (blockIdx.x >> 3);  // XCD swizzle (512 = 8*64)
  const int qt = bid & 15;
  const int bh = bid >> 4;
  const int b = bh >> 4, h = bh & 15;
  const size_t base = (size_t)bh * S_ * DK_;

  const int w = tid >> 6, lane = tid & 63;
  const int l31 = lane & 31, hh = lane >> 5, l7 = lane & 7;
  const int h4 = hh * 4;
  const int r2 = tid >> 3, e8 = (tid & 7) * 8;
  const int diagkt = qt * 2 + (w >> 1);

  // Q fragments (B-operand for swapped QK)
  short8 aq[4];
  {
    const us* qp = &Qh[base + (size_t)(qt * 128 + w * 32 + l31) * DK_ + hh * 8];
#pragma unroll
    for (int dk = 0; dk < 4; ++dk)
      aq[dk] = *reinterpret_cast<const short8*>(qp + dk * 16);
  }

  // loop-invariant LDS element offsets (XOR swizzle at 16B granularity)
  int rdK[2][4];
#pragma unroll
  for (int c = 0; c < 2; ++c)
#pragma unroll
    for (int dk = 0; dk < 4; ++dk)
      rdK[c][dk] = (c * 32 + l31) * 64 + (((dk * 2 + hh) ^ l7) << 3);
  const int wslot = ((tid & 7) ^ (r2 & 7)) << 3;
  const int wK0 = r2 * 64 + wslot, wK1 = (r2 + 32) * 64 + wslot;

  // prologue: stage tile 0
  short8 pk0, pk1, pv0, pv1;
  pk0 = *reinterpret_cast<const short8*>(&Kh[base + (size_t)r2 * DK_ + e8]);
  pk1 = *reinterpret_cast<const short8*>(&Kh[base + (size_t)(r2 + 32) * DK_ + e8]);
  pv0 = *reinterpret_cast<const short8*>(&VhTw[base + (size_t)r2 * S_ + e8]);
  pv1 = *reinterpret_cast<const short8*>(&VhTw[base + (size_t)(r2 + 32) * S_ + e8]);
  *reinterpret_cast<short8*>(&lK2[0][wK0]) = pk0;
  *reinterpret_cast<short8*>(&lK2[0][wK1]) = pk1;
  *reinterpret_cast<short8*>(&vT2[0][wK0]) = pv0;
  *reinterpret_cast<short8*>(&vT2[0][wK1]) = pv1;
  __syncthreads();

  f32x16 oacc[2];
  float lacc = 0.f;
#pragma unroll
  for (int c = 0; c < 2; ++c)
#pragma unroll
    for (int r = 0; r < 16; ++r) oacc[c][r] = 0.f;

  for (int kt = 0; kt < 32; ++kt) {
    const int cur = kt & 1;
    if (kt < 31) {
      int nt = kt + 1;
      pk0 = *reinterpret_cast<const short8*>(&Kh[base + (size_t)(nt * 64 + r2) * DK_ + e8]);
      pk1 = *reinterpret_cast<const short8*>(&Kh[base + (size_t)(nt * 64 + r2 + 32) * DK_ + e8]);
      pv0 = *reinterpret_cast<const short8*>(&VhTw[base + (size_t)r2 * S_ + nt * 64 + e8]);
      pv1 = *reinterpret_cast<const short8*>(&VhTw[base + (size_t)(r2 + 32) * S_ + nt * 64 + e8]);
    }

    // swapped QK^T: st_c[k=crow][q=l31] = mfma(A=K chunk c, B=Q)
    f32x16 st0, st1;
#pragma unroll
    for (int r = 0; r < 16; ++r) { st0[r] = 0.f; st1[r] = 0.f; }
    __builtin_amdgcn_s_setprio(1);
#pragma unroll
    for (int dk = 0; dk < 4; ++dk) {
      short8 k0 = *reinterpret_cast<const short8*>(&lK2[cur][rdK[0][dk]]);
      st0 = __builtin_amdgcn_mfma_f32_32x32x16_bf16(k0, aq[dk], st0, 0, 0, 0);
      short8 k1 = *reinterpret_cast<const short8*>(&lK2[cur][rdK[1][dk]]);
      st1 = __builtin_amdgcn_mfma_f32_32x32x16_bf16(k1, aq[dk], st1, 0, 0, 0);
    }
    __builtin_amdgcn_s_setprio(0);

    // streaming softmax fully in-register: e = 2^st, per-lane partial l
    float e0[16], e1[16];
#pragma unroll
    for (int r = 0; r < 16; ++r) {
      e0[r] = __builtin_amdgcn_exp2f(st0[r]);
      e1[r] = __builtin_amdgcn_exp2f(st1[r]);
      lacc += e0[r] + e1[r];
    }
    if (kt == diagkt) {  // raw diagonal P for epilogue correction
#pragma unroll
      for (int r = 0; r < 16; ++r) {
        int kk = (r & 3) + 8 * (r >> 2) + 4 * hh;
        float ev = (w & 1) ? e1[r] : e0[r];
        if (kk == l31) diagP[w * 32 + l31] = ev;
      }
    }

    // P -> bf16 A-frags via cvt_pk + permlane32_swap (no LDS round-trip)
    short8 pa[4];
#pragma unroll
    for (int ks = 0; ks < 4; ++ks) {
      const int ro = (ks & 1) * 8;
      unsigned d0, s0, d1, s1;
      if (ks < 2) {
        d0 = cvtpk(e0[ro + 0], e0[ro + 1]);
        s0 = cvtpk(e0[ro + 4], e0[ro + 5]);
        d1 = cvtpk(e0[ro + 2], e0[ro + 3]);
        s1 = cvtpk(e0[ro + 6], e0[ro + 7]);
      } else {
        d0 = cvtpk(e1[ro + 0], e1[ro + 1]);
        s0 = cvtpk(e1[ro + 4], e1[ro + 5]);
        d1 = cvtpk(e1[ro + 2], e1[ro + 3]);
        s1 = cvtpk(e1[ro + 6], e1[ro + 7]);
      }
      asm("v_permlane32_swap_b32 %0, %1" : "+v"(d0), "+v"(s0));
      asm("v_permlane32_swap_b32 %0, %1" : "+v"(d1), "+v"(s1));
      union { unsigned u[4]; short8 v; } pk;
      pk.u[0] = d0; pk.u[1] = d1; pk.u[2] = s0; pk.u[3] = s1;
      pa[ks] = pk.v;
    }

    // PV: O[q][d] += P * V'
    __builtin_amdgcn_s_setprio(1);
#pragma unroll
    for (int dc = 0; dc < 2; ++dc)
#pragma unroll
      for (int ks = 0; ks < 4; ++ks) {
        short8 bv = *reinterpret_cast<const short8*>(&vT2[cur][rdK[dc][ks]]);
        oacc[dc] = __builtin_amdgcn_mfma_f32_32x32x16_bf16(pa[ks], bv, oacc[dc], 0, 0, 0);
      }
    __builtin_amdgcn_s_setprio(0);

    if (kt < 31) {
      const int nx = cur ^ 1;
      *reinterpret_cast<short8*>(&lK2[nx][wK0]) = pk0;
      *reinterpret_cast<short8*>(&lK2[nx][wK1]) = pk1;
      *reinterpret_cast<short8*>(&vT2[nx][wK0]) = pv0;
      *reinterpret_cast<short8*>(&vT2[nx][wK1]) = pv1;
    }
    __syncthreads();
  }

  // total l per q: merge the two hh halves, broadcast via LDS
  lacc += __shfl_xor(lacc, 32, 64);
  if (hh == 0) lsum[w * 32 + l31] = lacc;
  __syncthreads();

  const float rb = rsum[b];
#pragma unroll
  for (int r = 0; r < 16; ++r) {
    const int q = w * 32 + (r & 3) + 8 * (r >> 2) + h4;
    const int qg = qt * 128 + q;
    const float rq = reaches[b * S_ + qg];
    const float contrib = (rb - rq) / (rb + 1e-9f) * (1.f - rq) * 100.f;
    const float corr = 0.999999f * diagP[q] * rq;
    const float linv = 1.0f / lsum[q];
#pragma unroll
    for (int dc = 0; dc < 2; ++dc) {
      int d = dc * 32 + l31;
      float vhv = bf2f(Vh[base + (size_t)qg * DK_ + d]);
      float pv = (oacc[dc][r] - corr * vhv) * linv;
      float o = (vhv - pv) * contrib;
      concat[((size_t)(b * S_ + qg)) * D_ + h * 64 + d] = f2bf(o);
    }
  }
}

extern "C" void kernel_launch(void* const* d_in, const int* in_sizes, int n_in,
                              void* d_out, int out_size, void* d_ws, size_t ws_size,
                              hipStream_t stream) {
  const float* q = (const float*)d_in[0];
  const float* k = (const float*)d_in[1];
  const float* v = (const float*)d_in[2];
  const float* reaches = (const float*)d_in[3];
  const float* Wq = (const float*)d_in[4];
  const float* Wk = (const float*)d_in[5];
  const float* Wv = (const float*)d_in[6];
  const float* Wo = (const float*)d_in[7];

  const size_t NQKV = (size_t)B_ * S_ * D_;
  const size_t NW = (size_t)D_ * D_;

  us* q_bf = (us*)d_ws;
  us* k_bf = q_bf + NQKV;
  us* v_bf = k_bf + NQKV;
  us* Wq_bf = v_bf + NQKV;
  us* Wk_bf = Wq_bf + NW;
  us* Wv_bf = Wk_bf + NW;
  us* Wo_bf = Wv_bf + NW;
  us* Qh = Wo_bf + NW;
  us* Kh = Qh + NQKV;
  us* Vh = Kh + NQKV;
  us* concat = Vh + NQKV;
  float* rs = (float*)(concat + NQKV);
  us* VhTw = q_bf;  // alias: q_bf dead after proj_gemm

  cvt_all<<<16385, 256, 0, stream>>>(q, k, v, Wq, Wk, Wv, Wo, reaches,
                                     q_bf, k_bf, v_bf, Wq_bf, Wk_bf, Wv_bf, Wo_bf, rs);

  proj_gemm<<<dim3(256, 3), 256, 0, stream>>>(q_bf, k_bf, v_bf, Wq_bf, Wk_bf, Wv_bf, Qh, Kh, Vh);
  transp_kernel<<<B_ * H_ * (S_ / 64), 256, 0, stream>>>(Vh, reaches, VhTw);

  attn_kernel<<<B_ * H_ * (S_ / 128), 256, 0, stream>>>(Qh, Kh, Vh, VhTw, reaches, rs, concat);

  wo_gemm<<<512, 256, 0, stream>>>(concat, Wo_bf, (float*)d_out);
}